// Round 5
// baseline (348.990 us; speedup 1.0000x reference)
//
#include <hip/hip_runtime.h>
#include <hip/hip_bf16.h>
#include <stdint.h>

typedef __bf16 bf16_t;
typedef __bf16 bf16x8 __attribute__((ext_vector_type(8)));
typedef float f32x4 __attribute__((ext_vector_type(4)));

constexpr int BATCH = 8192;
constexpr int M = 2 * BATCH;          // both branches stacked: 16384 rows

constexpr int K1 = 1216;                    // [e|r] 1200 -> 1216 (X zero-padded)
constexpr int LDC1 = 1664, NS1 = 1600;      // Y: stride 1664, store cols<1600
constexpr int LDA2 = 1664, KL2 = 1600;
constexpr int LDC2 = 1664, NS2 = 1600;
constexpr int LDA3 = 1664, KL3 = 1600;
constexpr int N3c = 1024;
constexpr int LDC3 = 1024, NS3 = 832;       // E: only cols<832 read downstream
constexpr int LDA4 = 1024, KL4 = 832;
constexpr int N4c = 1024;
constexpr int LDC4 = 1024, NS4 = 832;
constexpr int LDA5 = 1024, KL5 = 832, N5 = 512;
// weight buffers padded rows: G1/G2 need up to 1600 (+overstage to 1664·... keep 1792)
constexpr int NW1 = 1792, NW2 = 1792;

// ---------------------------------------------------------------- staging
__device__ __forceinline__ void gload_lds16(const void* g, void* l) {
  __builtin_amdgcn_global_load_lds(
      (const __attribute__((address_space(1))) void*)g,
      (__attribute__((address_space(3))) void*)l,
      16, 0, 0);
}

#define CFENCE() asm volatile("" ::: "memory")
#define BAR()  { CFENCE(); __builtin_amdgcn_s_barrier(); CFENCE(); }

// ---------------------------------------------------------------- prep: gather (2048 blocks) + converts (2048 blocks)
__device__ __forceinline__ void doconv(int idx, const float* __restrict__ src,
                                       bf16_t* __restrict__ dst, int Nr, int Kc, int Kp) {
  const int kp4 = Kp >> 2;
  const int r = idx / kp4;
  const int c = (idx - r * kp4) << 2;
  union { bf16_t h[4]; uint2 u; } pk;
#pragma unroll
  for (int j = 0; j < 4; ++j) {
    const int cc = c + j;
    const float v = (r < Nr && cc < Kc) ? src[(size_t)r * Kc + cc] : 0.f;
    pk.h[j] = (bf16_t)v;
  }
  *(uint2*)(dst + (size_t)r * Kp + c) = pk.u;
}

constexpr int CJ0 = NW1 * K1 / 4;
constexpr int CJ1 = CJ0 + NW2 * LDA2 / 4;
constexpr int CJ2 = CJ1 + N3c * LDA3 / 4;
constexpr int CJ3 = CJ2 + N4c * LDA4 / 4;
constexpr int CJ4 = CJ3 + N5 * LDA5 / 4;     // 2,109,440 total conv chunks
constexpr int GATHERB = 2048;                // 8 rows per block
constexpr int CONVB = 2048;                  // grid-strided conv
constexpr int PREPB = GATHERB + CONVB;

__global__ void prep_kernel(const int* __restrict__ a1, const int* __restrict__ r1,
                            const int* __restrict__ a2, const int* __restrict__ r2,
                            const float* __restrict__ ent, const float* __restrict__ rel,
                            bf16_t* __restrict__ X,
                            const float* __restrict__ pW1, const float* __restrict__ pW2,
                            const float* __restrict__ pW0, const float* __restrict__ iW1,
                            const float* __restrict__ iW2,
                            bf16_t* __restrict__ W1b, bf16_t* __restrict__ W2b,
                            bf16_t* __restrict__ W0b, bf16_t* __restrict__ iW1b,
                            bf16_t* __restrict__ iW2b) {
  if (blockIdx.x < GATHERB) {
    for (int r8 = 0; r8 < 8; ++r8) {
      const int row = blockIdx.x * 8 + r8;
      const int b   = row & (BATCH - 1);
      const int br  = row >> 13;
      const int eidx = br ? a2[b] : a1[b];
      const int ridx = br ? r2[b] : r1[b];
      const float* __restrict__ esrc = ent + (size_t)eidx * 800;
      const float* __restrict__ rsrc = rel + (size_t)ridx * 400;
      bf16_t* __restrict__ dst = X + (size_t)row * K1;
      for (int g = threadIdx.x; g < K1 / 4; g += 256) {
        const int c = g * 4;
        float4 v = make_float4(0.f, 0.f, 0.f, 0.f);
        if (c < 800) {                       // entity: _reg = clip(x+1, 0.05, 1e9)
          v = *(const float4*)(esrc + c);
          v.x = fminf(fmaxf(v.x + 1.f, 0.05f), 1e9f);
          v.y = fminf(fmaxf(v.y + 1.f, 0.05f), 1e9f);
          v.z = fminf(fmaxf(v.z + 1.f, 0.05f), 1e9f);
          v.w = fminf(fmaxf(v.w + 1.f, 0.05f), 1e9f);
        } else if (c < 1200) {
          v = *(const float4*)(rsrc + (c - 800));
        }
        union { bf16_t h[4]; uint2 u; } pk;
        pk.h[0] = (bf16_t)v.x; pk.h[1] = (bf16_t)v.y;
        pk.h[2] = (bf16_t)v.z; pk.h[3] = (bf16_t)v.w;
        *(uint2*)(dst + c) = pk.u;
      }
    }
  } else {
    for (int idx = (blockIdx.x - GATHERB) * 256 + threadIdx.x; idx < CJ4;
         idx += CONVB * 256) {
      if (idx < CJ0)      doconv(idx,        pW1, W1b, 1600, 1200, K1);
      else if (idx < CJ1) doconv(idx - CJ0,  pW2, W2b, 1600, 1600, LDA2);
      else if (idx < CJ2) doconv(idx - CJ1,  pW0, W0b,  800, 1600, LDA3);
      else if (idx < CJ3) doconv(idx - CJ2,  iW1, iW1b, 800,  800, LDA4);
      else                doconv(idx - CJ3,  iW2, iW2b, 400,  800, LDA5);
    }
  }
}

enum { ACT_RELU = 0, ACT_REG = 1 };

// ---------------------------------------------------------------- 8-phase pipelined GEMM body
// Block tile: 256(M) x NFR*64(N). 512 thr = 8 waves (2m x 4n), wave tile 128 x NFR*16. BK=64.
// LDS: 8 slots of [256 rows][32 k] bf16 = 128 KiB (B slots always staged 256 rows wide,
// so staging + vmcnt gates are identical for NFR=3 and NFR=4).
// Swizzle: chunk pos = g ^ ((row>>1)&3) -> 2-way bank access (free, m136).
// Gates: vmcnt(8) at end of ph2 and ph4 (counted, never 0 mid-loop); raw s_barrier only.
template <int ACT, int NFR>
__device__ __forceinline__
void gemm_body(const bf16_t* __restrict__ A, const bf16_t* __restrict__ Bw,
               const float* __restrict__ bias, int Nbias, bf16_t* __restrict__ Cb,
               int lda, int Nstore, int ldc, int NT, int bm, int col0,
               bf16_t* ldsbase, int t) {
  const int lane = t & 63;
  const int wv = t >> 6;
  const int wm = wv >> 2, wn = wv & 3;
  const int l15 = lane & 15;
  const int kbs = (((lane >> 4) ^ ((l15 >> 1) & 3)) << 4);

  const int srow = t >> 2;
  const int skc  = (t & 3) ^ ((t >> 3) & 3);
  const bf16_t* aR0 = A  + (size_t)(bm * 256 + srow) * lda + skc * 8;
  const bf16_t* aR1 = aR0 + (size_t)128 * lda;
  const bf16_t* bR0 = Bw + (size_t)(col0 + srow) * lda + skc * 8;
  const bf16_t* bR1 = bR0 + (size_t)128 * lda;
  const int ldsb0 = (wv * 64) * 16;
  const int ldsb1 = (512 + wv * 64) * 16;

  auto SLOT = [&](int s) { return ldsbase + s * 8192; };
  auto STAGE = [&](const bf16_t* r0p, const bf16_t* r1p, int kOff, bf16_t* slot) {
    gload_lds16(r0p + kOff, (char*)slot + ldsb0);
    gload_lds16(r1p + kOff, (char*)slot + ldsb1);
  };

  f32x4 acc[8][NFR];
#pragma unroll
  for (int i = 0; i < 8; ++i)
#pragma unroll
    for (int j = 0; j < NFR; ++j) acc[i][j] = f32x4{0.f, 0.f, 0.f, 0.f};

  STAGE(aR0, aR1, 0, SLOT(0));
  STAGE(bR0, bR1, 0, SLOT(2));
  STAGE(aR0, aR1, 32, SLOT(1));
  STAGE(bR0, bR1, 32, SLOT(3));
  if (NT > 1) {
    STAGE(aR0, aR1, 64, SLOT(4));
    STAGE(bR0, bR1, 64, SLOT(6));
    asm volatile("s_waitcnt vmcnt(8)" ::: "memory");
  } else {
    asm volatile("s_waitcnt vmcnt(4)" ::: "memory");
  }
  __builtin_amdgcn_s_barrier();
  CFENCE();

  bf16x8 bfr[NFR];
  int db = 0;
  for (int kt = 0; kt < NT; ++kt, db ^= 1) {
    const bool p1 = (kt + 1) < NT;
    const bool p2 = (kt + 2) < NT;
    bf16_t* const cur = SLOT(db * 4);
    bf16_t* const nxt = SLOT((db ^ 1) * 4);

    // ---- phase 1: khalf0, mhalf0 (+ B khalf0 reads); stage A1(kt+1)
    {
      const char* sA = (const char*)(cur);
      const char* sB = (const char*)(cur + 2 * 8192);
      bf16x8 af[4];
#pragma unroll
      for (int i = 0; i < 4; ++i)
        af[i] = *(const bf16x8*)(sA + ((wm * 128 + i * 16 + l15) << 6) + kbs);
#pragma unroll
      for (int i = 0; i < NFR; ++i)
        bfr[i] = *(const bf16x8*)(sB + ((wn * (NFR * 16) + i * 16 + l15) << 6) + kbs);
      if (p1) STAGE(aR0, aR1, (kt + 1) * 64 + 32, nxt + 1 * 8192);
      BAR();
      __builtin_amdgcn_s_setprio(1);
#pragma unroll
      for (int i = 0; i < 4; ++i)
#pragma unroll
        for (int j = 0; j < NFR; ++j)
          acc[i][j] = __builtin_amdgcn_mfma_f32_16x16x32_bf16(af[i], bfr[j], acc[i][j], 0, 0, 0);
      __builtin_amdgcn_s_setprio(0);
      BAR();
    }
    // ---- phase 2: khalf0, mhalf1; stage B1(kt+1); mid-gate
    {
      const char* sA = (const char*)(cur);
      bf16x8 af[4];
#pragma unroll
      for (int i = 0; i < 4; ++i)
        af[i] = *(const bf16x8*)(sA + ((wm * 128 + (4 + i) * 16 + l15) << 6) + kbs);
      if (p1) STAGE(bR0, bR1, (kt + 1) * 64 + 32, nxt + 3 * 8192);
      BAR();
      __builtin_amdgcn_s_setprio(1);
#pragma unroll
      for (int i = 0; i < 4; ++i)
#pragma unroll
        for (int j = 0; j < NFR; ++j)
          acc[4 + i][j] = __builtin_amdgcn_mfma_f32_16x16x32_bf16(af[i], bfr[j], acc[4 + i][j], 0, 0, 0);
      __builtin_amdgcn_s_setprio(0);
      if (p1) asm volatile("s_waitcnt vmcnt(8)" ::: "memory");
      else    asm volatile("s_waitcnt vmcnt(0)" ::: "memory");
      BAR();
    }
    // ---- phase 3: khalf1, mhalf0 (+ B khalf1 reads); stage A0(kt+2)
    {
      const char* sA = (const char*)(cur + 1 * 8192);
      const char* sB = (const char*)(cur + 3 * 8192);
      bf16x8 af[4];
#pragma unroll
      for (int i = 0; i < 4; ++i)
        af[i] = *(const bf16x8*)(sA + ((wm * 128 + i * 16 + l15) << 6) + kbs);
#pragma unroll
      for (int i = 0; i < NFR; ++i)
        bfr[i] = *(const bf16x8*)(sB + ((wn * (NFR * 16) + i * 16 + l15) << 6) + kbs);
      if (p2) STAGE(aR0, aR1, (kt + 2) * 64, cur + 0 * 8192);
      BAR();
      __builtin_amdgcn_s_setprio(1);
#pragma unroll
      for (int i = 0; i < 4; ++i)
#pragma unroll
        for (int j = 0; j < NFR; ++j)
          acc[i][j] = __builtin_amdgcn_mfma_f32_16x16x32_bf16(af[i], bfr[j], acc[i][j], 0, 0, 0);
      __builtin_amdgcn_s_setprio(0);
      BAR();
    }
    // ---- phase 4: khalf1, mhalf1; stage B0(kt+2); end-gate
    {
      const char* sA = (const char*)(cur + 1 * 8192);
      bf16x8 af[4];
#pragma unroll
      for (int i = 0; i < 4; ++i)
        af[i] = *(const bf16x8*)(sA + ((wm * 128 + (4 + i) * 16 + l15) << 6) + kbs);
      if (p2) STAGE(bR0, bR1, (kt + 2) * 64, cur + 2 * 8192);
      BAR();
      __builtin_amdgcn_s_setprio(1);
#pragma unroll
      for (int i = 0; i < 4; ++i)
#pragma unroll
        for (int j = 0; j < NFR; ++j)
          acc[4 + i][j] = __builtin_amdgcn_mfma_f32_16x16x32_bf16(af[i], bfr[j], acc[4 + i][j], 0, 0, 0);
      __builtin_amdgcn_s_setprio(0);
      if (p1) {
        if (p2) asm volatile("s_waitcnt vmcnt(8)" ::: "memory");
        else    asm volatile("s_waitcnt vmcnt(4)" ::: "memory");
      }
      BAR();
    }
  }

  // epilogue: D frag col = lane&15, row = (lane>>4)*4 + j
  const int r0 = bm * 256 + wm * 128 + ((lane >> 4) * 4);
  const int c0 = col0 + wn * (NFR * 16) + l15;
#pragma unroll
  for (int ni = 0; ni < NFR; ++ni) {
    const int col = c0 + ni * 16;
    const float bv = (col < Nbias) ? bias[col] : 0.f;
    const bool cok = (col < Nstore);
#pragma unroll
    for (int mi = 0; mi < 8; ++mi) {
#pragma unroll
      for (int j = 0; j < 4; ++j) {
        float v = acc[mi][ni][j] + bv;
        if (ACT == ACT_RELU) v = fmaxf(v, 0.f);
        else                 v = fminf(fmaxf(v + 1.f, 0.05f), 1e9f);
        if (cok) Cb[(size_t)(r0 + mi * 16 + j) * ldc + col] = (bf16_t)v;
      }
    }
  }
}

// MIXED: gridN=8, bn<7 -> 192-wide (NFR=3), bn=7 -> 256-wide (NFR=4); col0 = bn*192.
// !MIXED: uniform 256-wide tiles, col0 = bn*256.
template <int ACT, bool MIXED>
__global__ __launch_bounds__(512)
void gemm256(const bf16_t* __restrict__ A, const bf16_t* __restrict__ Bw,
             const float* __restrict__ bias, int Nbias,
             bf16_t* __restrict__ Cb,
             int lda, int Nstore, int ldc, int NT, int gridN) {
  __shared__ __align__(16) bf16_t lds[8][8192];
  const int nwg = gridDim.x;
  const int id = blockIdx.x;
  const int swz = (id & 7) * (nwg >> 3) + (id >> 3);   // XCD-aware (nwg % 8 == 0)
  const int bn = swz % gridN, bm = swz / gridN;
  const int t = threadIdx.x;
  if (MIXED) {
    const int col0 = bn * 192;
    if (bn < gridN - 1)
      gemm_body<ACT, 3>(A, Bw, bias, Nbias, Cb, lda, Nstore, ldc, NT, bm, col0, &lds[0][0], t);
    else
      gemm_body<ACT, 4>(A, Bw, bias, Nbias, Cb, lda, Nstore, ldc, NT, bm, col0, &lds[0][0], t);
  } else {
    gemm_body<ACT, 4>(A, Bw, bias, Nbias, Cb, lda, Nstore, ldc, NT, bm, bn * 256, &lds[0][0], t);
  }
}

// ---------------------------------------------------------------- G5+combine fused, double-buffered:
// Block (bn 0..3, bm 0..63): both branches' 128x128 logit tiles (B staged once),
// stage(t+1) issued before compute(t); __syncthreads (implicit vmcnt0 drain) per iter.
constexpr int NT5 = KL5 / 64;   // 13
__global__ __launch_bounds__(256)
void g5_combine(const bf16_t* __restrict__ H, const bf16_t* __restrict__ Wb,
                const float* __restrict__ ib2, const bf16_t* __restrict__ E,
                float* __restrict__ out) {
  __shared__ __align__(16) bf16_t As1[2][8192];
  __shared__ __align__(16) bf16_t As2[2][8192];
  __shared__ __align__(16) bf16_t Bs[2][8192];

  const int bn = blockIdx.x, bm = blockIdx.y;
  const int t = threadIdx.x;
  const int lane = t & 63;
  const int wv = t >> 6;
  const int wm = wv >> 1, wn = wv & 1;

  f32x4 acc1[4][4], acc2[4][4];
#pragma unroll
  for (int i = 0; i < 4; ++i)
#pragma unroll
    for (int j = 0; j < 4; ++j) { acc1[i][j] = f32x4{0.f,0.f,0.f,0.f}; acc2[i][j] = f32x4{0.f,0.f,0.f,0.f}; }

  const size_t a1Base = (size_t)(bm * 128) * LDA5;
  const size_t a2Base = (size_t)(8192 + bm * 128) * LDA5;
  const size_t bBase  = (size_t)(bn * 128) * LDA5;

  auto stage = [&](int db, int kt) {
#pragma unroll
    for (int q = 0; q < 4; ++q) {
      const int lin = q * 256 + t;
      const int row = lin >> 3;
      const int kc = ((lin & 7) ^ (row & 7)) * 8;          // swizzled source chunk
      const int lofs = (q * 256 + wv * 64) * 16;
      gload_lds16(H + a1Base + (size_t)row * LDA5 + kt + kc, (char*)As1[db] + lofs);
      gload_lds16(H + a2Base + (size_t)row * LDA5 + kt + kc, (char*)As2[db] + lofs);
      gload_lds16(Wb + bBase + (size_t)row * LDA5 + kt + kc, (char*)Bs[db] + lofs);
    }
  };

  stage(0, 0);
  __syncthreads();                      // drains vmcnt(0): buf0 ready
  int db = 0;
  for (int it = 0; it < NT5; ++it) {
    if (it + 1 < NT5) stage(db ^ 1, (it + 1) * 64);   // issue early
#pragma unroll
    for (int s = 0; s < 2; ++s) {
      const int crd = s * 4 + (lane >> 4);
      const int k0 = (crd ^ (lane & 7)) * 8;           // swizzled read chunk
      bf16x8 af1[4], af2[4], bf[4];
#pragma unroll
      for (int i = 0; i < 4; ++i) {
        const int ra = wm * 64 + i * 16 + (lane & 15);
        af1[i] = *(const bf16x8*)(As1[db] + ra * 64 + k0);
        af2[i] = *(const bf16x8*)(As2[db] + ra * 64 + k0);
        const int rb = wn * 64 + i * 16 + (lane & 15);
        bf[i] = *(const bf16x8*)(Bs[db] + rb * 64 + k0);
      }
#pragma unroll
      for (int mi = 0; mi < 4; ++mi)
#pragma unroll
        for (int ni = 0; ni < 4; ++ni) {
          acc1[mi][ni] = __builtin_amdgcn_mfma_f32_16x16x32_bf16(af1[mi], bf[ni], acc1[mi][ni], 0, 0, 0);
          acc2[mi][ni] = __builtin_amdgcn_mfma_f32_16x16x32_bf16(af2[mi], bf[ni], acc2[mi][ni], 0, 0, 0);
        }
    }
    __syncthreads();                    // drain wait-late: next buf landed; reads of cur done
    db ^= 1;
  }

  // epilogue: softmax over 2 branches + weighted E sums
  const int rloc0 = wm * 64 + ((lane >> 4) * 4);
  const int cloc0 = wn * 64 + (lane & 15);
#pragma unroll
  for (int ni = 0; ni < 4; ++ni) {
    const int d = bn * 128 + cloc0 + ni * 16;
    if (d >= 400) continue;
    const float bv = ib2[d];
#pragma unroll
    for (int mi = 0; mi < 4; ++mi) {
#pragma unroll
      for (int j = 0; j < 4; ++j) {
        const int b = bm * 128 + rloc0 + mi * 16 + j;
        const float l1 = acc1[mi][ni][j] + bv;
        const float l2 = acc2[mi][ni][j] + bv;
        const float att1 = 1.f / (1.f + expf(l2 - l1));
        const float att2 = 1.f - att1;
        const bf16_t* E1 = E + (size_t)b * LDC3;
        const bf16_t* E2 = E + (size_t)(8192 + b) * LDC3;
        out[(size_t)b * 400 + d] =
            att1 * (float)E1[d] + att2 * (float)E2[d];
        out[(size_t)8192 * 400 + (size_t)b * 400 + d] =
            att1 * (float)E1[400 + d] + att2 * (float)E2[400 + d];
      }
    }
  }
}

// ----------------------------------------------------------------
extern "C" void kernel_launch(void* const* d_in, const int* in_sizes, int n_in,
                              void* d_out, int out_size, void* d_ws, size_t ws_size,
                              hipStream_t stream) {
  const int* a1 = (const int*)d_in[0];
  const int* r1 = (const int*)d_in[1];
  const int* a2 = (const int*)d_in[2];
  const int* r2 = (const int*)d_in[3];
  const float* ent = (const float*)d_in[4];
  const float* rel = (const float*)d_in[5];
  const float* pW1 = (const float*)d_in[6];
  const float* pb1 = (const float*)d_in[7];
  const float* pW2 = (const float*)d_in[8];
  const float* pb2 = (const float*)d_in[9];
  const float* pW0 = (const float*)d_in[10];
  const float* pb0 = (const float*)d_in[11];
  const float* iW1 = (const float*)d_in[12];
  const float* ib1 = (const float*)d_in[13];
  const float* iW2 = (const float*)d_in[14];
  const float* ib2 = (const float*)d_in[15];

  char* ws = (char*)d_ws;
  size_t o = 0;
  auto take = [&](size_t bytes) { char* p = ws + o; o += (bytes + 255) & ~(size_t)255; return p; };
  bf16_t* W1b  = (bf16_t*)take((size_t)NW1 * K1 * 2);
  bf16_t* W2b  = (bf16_t*)take((size_t)NW2 * LDA2 * 2);
  bf16_t* W0b  = (bf16_t*)take((size_t)N3c * LDA3 * 2);
  bf16_t* iW1b = (bf16_t*)take((size_t)N4c * LDA4 * 2);
  bf16_t* iW2b = (bf16_t*)take((size_t)N5 * LDA5 * 2);
  char* bufX = take((size_t)M * K1 * 2);   // X bf16 [M,1216]; later E bf16 [M,1024]
  char* bufY = take((size_t)M * LDC1 * 2); // Y bf16 [M,1664]; later H bf16 [M,1024]
  char* bufZ = take((size_t)M * LDC2 * 2); // Z bf16 [M,1664]

  bf16_t* Xb = (bf16_t*)bufX;
  bf16_t* Yb = (bf16_t*)bufY;
  bf16_t* Zb = (bf16_t*)bufZ;
  bf16_t* Eb = (bf16_t*)bufX;   // reuse: X dead after G1
  bf16_t* Hb = (bf16_t*)bufY;   // reuse: Y dead after G2

  prep_kernel<<<dim3(PREPB), 256, 0, stream>>>(a1, r1, a2, r2, ent, rel, Xb,
                                               pW1, pW2, pW0, iW1, iW2,
                                               W1b, W2b, W0b, iW1b, iW2b);

  // G1: Y = relu(X W1^T + b1)   mixed 7x192+256 tiles, grid 512 = exactly 2 waves
  gemm256<ACT_RELU, true><<<dim3(8 * (M / 256)), 512, 0, stream>>>(
      Xb, W1b, pb1, 1600, Yb, K1, NS1, LDC1, K1 / 64, 8);
  // G2: Z = relu(Y W2^T + b2)   mixed tiles, kloop=1600
  gemm256<ACT_RELU, true><<<dim3(8 * (M / 256)), 512, 0, stream>>>(
      Yb, W2b, pb2, 1600, Zb, LDA2, NS2, LDC2, KL2 / 64, 8);
  // G3: E = reg(Z W0^T + b0)    uniform 4x256, grid 256 (1/CU)
  gemm256<ACT_REG, false><<<dim3(4 * (M / 256)), 512, 0, stream>>>(
      Zb, W0b, pb0, 800, Eb, LDA3, NS3, LDC3, KL3 / 64, 4);
  // G4: H = relu(E iW1^T + ib1) uniform 4x256, grid 256
  gemm256<ACT_RELU, false><<<dim3(4 * (M / 256)), 512, 0, stream>>>(
      Eb, iW1b, ib1, 800, Hb, LDA4, NS4, LDC4, KL4 / 64, 4);
  // G5 + softmax + combine, fused (double-buffered)
  g5_combine<<<dim3(N5 / 128, BATCH / 128), 256, 0, stream>>>(
      Hb, iW2b, ib2, Eb, (float*)d_out);
}